// Round 1
// baseline (100.185 us; speedup 1.0000x reference)
//
#include <hip/hip_runtime.h>
#include <math.h>

#define BB 64
#define DD 512
#define HH 8
#define EPS 1e-8f

// Raw v_rcp_f32 (~1 ulp). Used identically for the softmax max (m) and the
// per-j r, so r-m cancels exactly at the argmin (same instruction, same input).
__device__ __forceinline__ float fast_rcp(float d) {
    return __builtin_amdgcn_rcpf(d);
}

// Block = 512 threads: (ii, jc) = (tid & 255, tid >> 8).
// Each block handles 256 i's of one (b, h); each jc-half handles 256 j's.
// j-split doubles resident waves -> 32 waves/CU (100% of thread slots).
__global__ __launch_bounds__(512, 8) void flattn_kernel(
    const float* __restrict__ x,
    const float* __restrict__ alphas,
    const float* __restrict__ betas,
    float* __restrict__ out)
{
    const int b  = blockIdx.x;     // batch
    const int ic = blockIdx.y;     // i-chunk (0..1)
    const int h  = blockIdx.z;     // head

    __shared__ float xs[DD];
    __shared__ float mind_sh[2][256];
    __shared__ float ss_sh[256];
    __shared__ float sx_sh[256];

    const int tid = threadIdx.x;
    const int ii  = tid & 255;
    const int jc  = tid >> 8;          // wave-uniform (waves 0-3 -> 0, 4-7 -> 1)
    const int i   = ic * 256 + ii;

    const float a0 = alphas[h * 3 + 0];
    const float a1 = alphas[h * 3 + 1];
    const float a2 = alphas[h * 3 + 2];
    const float b0 = betas[h * 3 + 0];
    const float b1 = betas[h * 3 + 1];
    const float b2 = betas[h * 3 + 2];

    xs[tid] = x[b * DD + tid];
    __syncthreads();

    const float xi = xs[i];
    const float c  = b0 - fmaf(a1, xi, b1);   // q_j - k_i = a0*x_j + c

    const int j0 = jc * 256;

    // Pass 1: local min over this jc-half (fma + min(abs) = 2 VALU/j)
    float mind = 3.0e38f;
    #pragma unroll 4
    for (int j = j0; j < j0 + 256; j += 4) {
        float4 x4 = *(const float4*)&xs[j];    // ds_read_b128 broadcast
        mind = fminf(mind, fabsf(fmaf(a0, x4.x, c)));
        mind = fminf(mind, fabsf(fmaf(a0, x4.y, c)));
        mind = fminf(mind, fabsf(fmaf(a0, x4.z, c)));
        mind = fminf(mind, fabsf(fmaf(a0, x4.w, c)));
    }
    mind_sh[jc][ii] = mind;
    __syncthreads();

    // Global min -> shared m for both halves (no rescale factors needed).
    mind = fminf(mind_sh[0][ii], mind_sh[1][ii]);
    const float m = fast_rcp(mind + EPS);      // same expr as pass 2's r
    const float log2e = 1.4426950408889634f;
    const float negml = -m * log2e;

    // Peaked-softmax skip threshold: terms with r_j < m - 27 have weight
    // < e^-27 ~ 1.9e-12; total dropped mass < 512*1.9e-12 ~ 1e-9 against a
    // denominator >= 1 (argmin term is exactly 1).  Fire iff |t| < dcutp.
    // Exact math: 1/(m-27) = (mind+EPS)/(1-27*(mind+EPS)) > mind+EPS, with
    // relative margin 27*(mind+EPS) >> rcp's 1-ulp error, so the argmin
    // always fires.  Flat regime (m <= 28): keep dcutp = +inf, old behavior.
    float dcutp = 3.0e38f;
    if (m > 28.0f) dcutp = fast_rcp(m - 27.0f) - EPS;

    // Pass 2: softmax-weighted sums over this jc-half, skipping the
    // transcendental cluster (rcp+exp2, ~16 of 26 cy/j) when no lane fires.
    //   sum_j s_j*(a2*x_j+b2) = a2*sx + b2*ss  (vs[] folded out)
    float ss = 0.0f, sx = 0.0f;
    for (int j = j0; j < j0 + 256; j += 4) {
        float4 x4 = *(const float4*)&xs[j];
        float t0 = fmaf(a0, x4.x, c);
        float t1 = fmaf(a0, x4.y, c);
        float t2 = fmaf(a0, x4.z, c);
        float t3 = fmaf(a0, x4.w, c);
        if (fabsf(t0) < dcutp) {
            float r = fast_rcp(fabsf(t0) + EPS);
            float s = __builtin_amdgcn_exp2f(fmaf(r, log2e, negml));
            ss += s; sx = fmaf(s, x4.x, sx);
        }
        if (fabsf(t1) < dcutp) {
            float r = fast_rcp(fabsf(t1) + EPS);
            float s = __builtin_amdgcn_exp2f(fmaf(r, log2e, negml));
            ss += s; sx = fmaf(s, x4.y, sx);
        }
        if (fabsf(t2) < dcutp) {
            float r = fast_rcp(fabsf(t2) + EPS);
            float s = __builtin_amdgcn_exp2f(fmaf(r, log2e, negml));
            ss += s; sx = fmaf(s, x4.z, sx);
        }
        if (fabsf(t3) < dcutp) {
            float r = fast_rcp(fabsf(t3) + EPS);
            float s = __builtin_amdgcn_exp2f(fmaf(r, log2e, negml));
            ss += s; sx = fmaf(s, x4.w, sx);
        }
    }

    // Merge the two jc-halves via LDS, then one atomic per (i, h).
    if (jc == 1) { ss_sh[ii] = ss; sx_sh[ii] = sx; }
    __syncthreads();
    if (jc == 0) {
        ss += ss_sh[ii];
        sx += sx_sh[ii];
        const float scale = 0.04419417382415922f;   // 1/sqrt(512)
        float sv  = fmaf(a2, sx, b2 * ss);
        float att = sv * fast_rcp(ss) * scale;
        if (h == 0) att += xi;
        atomicAdd(&out[b * DD + i], att);
    }
}

extern "C" void kernel_launch(void* const* d_in, const int* in_sizes, int n_in,
                              void* d_out, int out_size, void* d_ws, size_t ws_size,
                              hipStream_t stream) {
    const float* x      = (const float*)d_in[0];
    const float* alphas = (const float*)d_in[1];
    const float* betas  = (const float*)d_in[2];
    float* out = (float*)d_out;

    hipMemsetAsync(out, 0, (size_t)out_size * sizeof(float), stream);

    dim3 grid(BB, 2, HH);
    dim3 block(512);
    flattn_kernel<<<grid, block, 0, stream>>>(x, alphas, betas, out);
}

// Round 2
// 98.689 us; speedup vs baseline: 1.0152x; 1.0152x over previous
//
#include <hip/hip_runtime.h>
#include <math.h>

#define BB 64
#define DD 512
#define HH 8
#define EPS 1e-8f

// Cross-kernel buffers (avoids d_ws size assumptions; legal under graph capture).
__device__ float g_xsorted[BB][DD];
__device__ int   g_perm[BB][DD];

// Raw v_rcp_f32 (~1 ulp). Same instruction+input for m and pass-2 r at the
// argmin -> exact cancellation -> no exp overflow.
__device__ __forceinline__ float fast_rcp(float d) {
    return __builtin_amdgcn_rcpf(d);
}

// ---------------- kernel 1: per-b bitonic sort (ascending) + index perm -----
__global__ __launch_bounds__(DD) void sort_kernel(const float* __restrict__ x)
{
    const int b   = blockIdx.x;
    const int tid = threadIdx.x;
    __shared__ float sv[DD];
    __shared__ int   si[DD];
    sv[tid] = x[b * DD + tid];
    si[tid] = tid;
    __syncthreads();
    for (int k = 2; k <= DD; k <<= 1) {
        for (int j = k >> 1; j > 0; j >>= 1) {
            const int ixj = tid ^ j;
            if (ixj > tid) {
                const bool up = ((tid & k) == 0);
                float v0 = sv[tid], v1 = sv[ixj];
                bool sw = up ? (v0 > v1) : (v0 < v1);
                if (sw) {
                    int i0 = si[tid], i1 = si[ixj];
                    sv[tid] = v1; sv[ixj] = v0;
                    si[tid] = i1; si[ixj] = i0;
                }
            }
            __syncthreads();
        }
    }
    g_xsorted[b][tid] = sv[tid];
    g_perm[b][tid]    = si[tid];
}

// ---------------- kernel 2: attention ---------------------------------------
// Block = 512: (ii, jc) = (tid & 255, tid >> 8). Lane ii handles the i whose
// x-value has sorted rank ic*256+ii -> adjacent lanes have adjacent x_i, so
// window locations/sizes are wave-coherent and flat i's cluster into few waves.
__global__ __launch_bounds__(512, 8) void flattn_kernel(
    const float* __restrict__ x,
    const float* __restrict__ alphas,
    const float* __restrict__ betas,
    float* __restrict__ out)
{
    const int b  = blockIdx.x;
    const int ic = blockIdx.y;
    const int h  = blockIdx.z;

    __shared__ float xs[DD];           // original order (dense path, bitwise r0)
    __shared__ float xss[DD];          // sorted order  (window path)
    __shared__ float mind_sh[2][256];
    __shared__ float ss_sh[256];
    __shared__ float sx_sh[256];

    const int tid  = threadIdx.x;
    const int ii   = tid & 255;
    const int jc   = tid >> 8;         // wave-uniform
    const int rank = ic * 256 + ii;

    const float a0 = alphas[h * 3 + 0];
    const float a1 = alphas[h * 3 + 1];
    const float a2 = alphas[h * 3 + 2];
    const float b0 = betas[h * 3 + 0];
    const float b1 = betas[h * 3 + 1];
    const float b2 = betas[h * 3 + 2];

    xs[tid]  = x[b * DD + tid];
    xss[tid] = g_xsorted[b][tid];
    __syncthreads();

    const float xi = xss[rank];                 // bitwise x[perm[rank]]
    const float c  = b0 - fmaf(a1, xi, b1);     // t_j = a0*x_j + c

    // ---- prelude (all lanes): crossing search + m-hat + window bounds ------
    const float ra0 = fast_rcp(a0);
    const float u   = -c * ra0;                 // |t| minimized at x ~= u

    // pos = count of sorted elements < u  (branchless, clamped probes)
    int pos = 0;
    #pragma unroll
    for (int s = 512; s > 0; s >>= 1) {
        int p = pos + s;
        float v = xss[(p <= 512 ? p : 512) - 1];
        pos = (p <= 512 && v < u) ? p : pos;
    }
    // m-hat from fma-evaluated candidates around pos. Subset-min >= true min
    // => mhat <= m_true, so the 1/(mhat-30) window PROVABLY contains every j
    // with weight > e^-30 and the argmin itself.
    float mind_hat = 3.0e38f;
    #pragma unroll
    for (int q = -2; q <= 1; ++q) {
        int cidx = pos + q;
        if (cidx >= 0 && cidx < DD)
            mind_hat = fminf(mind_hat, fabsf(fmaf(a0, xss[cidx], c)));
    }
    const float mhat = fast_rcp(mind_hat + EPS);

    const float th  = fast_rcp(fmaxf(mhat - 30.0f, 1e-30f));
    const float tha = fmaf(th * 1.0001f, ra0, 1e-6f);   // x-space half-width + fma-rounding slack
    const float xlo = u - tha;
    const float xhi = u + tha;

    int lo = 0, hi = 0;            // lo = count(< xlo), hi = count(<= xhi)
    #pragma unroll
    for (int s = 512; s > 0; s >>= 1) {
        int pl = lo + s, ph = hi + s;
        float vl = xss[(pl <= 512 ? pl : 512) - 1];
        float vh = xss[(ph <= 512 ? ph : 512) - 1];
        lo = (pl <= 512 && vl <  xlo) ? pl : lo;
        hi = (ph <= 512 && vh <= xhi) ? ph : hi;
    }
    lo = max(lo - 2, 0);           // widen: search/rounding insurance
    hi = min(hi + 2, DD);
    const int len = hi - lo;

    // Wave-uniform path choice; identical for the jc=0/jc=1 waves of the same
    // ii-range (no jc-dependence), so mind_sh/ss_sh pairing stays consistent.
    const bool lane_peaked = (a0 > 1e-6f) && (mhat > 60.0f) && (len <= 64);
    const bool peaked = __all(lane_peaked);

    const float log2e = 1.4426950408889634f;

    // ---- pass 1: min |t| (window or dense) ---------------------------------
    float md = 3.0e38f;
    int wl = 0, wh = 0;
    const int j0 = jc * 256;
    if (peaked) {
        const int mid = lo + ((len + 1) >> 1);
        wl = jc ? mid : lo;
        wh = jc ? hi  : mid;
        for (int k = wl; k < wh; ++k)
            md = fminf(md, fabsf(fmaf(a0, xss[k], c)));
    } else {
        #pragma unroll 4
        for (int j = j0; j < j0 + 256; j += 4) {
            float4 x4 = *(const float4*)&xs[j];
            md = fminf(md, fabsf(fmaf(a0, x4.x, c)));
            md = fminf(md, fabsf(fmaf(a0, x4.y, c)));
            md = fminf(md, fabsf(fmaf(a0, x4.z, c)));
            md = fminf(md, fabsf(fmaf(a0, x4.w, c)));
        }
    }
    mind_sh[jc][ii] = md;
    __syncthreads();

    const float mind  = fminf(mind_sh[0][ii], mind_sh[1][ii]);
    const float m     = fast_rcp(mind + EPS);   // same expr as pass-2 r
    const float negml = -m * log2e;

    // ---- pass 2: softmax-weighted sums -------------------------------------
    float ss = 0.0f, sx = 0.0f;
    if (peaked) {
        for (int k = wl; k < wh; ++k) {
            float xv = xss[k];
            float t  = fmaf(a0, xv, c);
            float r  = fast_rcp(fabsf(t) + EPS);
            float s  = __builtin_amdgcn_exp2f(fmaf(r, log2e, negml));
            ss += s; sx = fmaf(s, xv, sx);
        }
    } else {
        #pragma unroll 2
        for (int j = j0; j < j0 + 256; j += 4) {
            float4 x4 = *(const float4*)&xs[j];
            {
                float t = fmaf(a0, x4.x, c);
                float r = fast_rcp(fabsf(t) + EPS);
                float s = __builtin_amdgcn_exp2f(fmaf(r, log2e, negml));
                ss += s; sx = fmaf(s, x4.x, sx);
            }
            {
                float t = fmaf(a0, x4.y, c);
                float r = fast_rcp(fabsf(t) + EPS);
                float s = __builtin_amdgcn_exp2f(fmaf(r, log2e, negml));
                ss += s; sx = fmaf(s, x4.y, sx);
            }
            {
                float t = fmaf(a0, x4.z, c);
                float r = fast_rcp(fabsf(t) + EPS);
                float s = __builtin_amdgcn_exp2f(fmaf(r, log2e, negml));
                ss += s; sx = fmaf(s, x4.z, sx);
            }
            {
                float t = fmaf(a0, x4.w, c);
                float r = fast_rcp(fabsf(t) + EPS);
                float s = __builtin_amdgcn_exp2f(fmaf(r, log2e, negml));
                ss += s; sx = fmaf(s, x4.w, sx);
            }
        }
    }

    // ---- merge jc-halves, one atomic per (i, h) ----------------------------
    if (jc == 1) { ss_sh[ii] = ss; sx_sh[ii] = sx; }
    __syncthreads();
    if (jc == 0) {
        ss += ss_sh[ii];
        sx += sx_sh[ii];
        const float scale = 0.04419417382415922f;   // 1/sqrt(512)
        float sv  = fmaf(a2, sx, b2 * ss);
        float att = sv * fast_rcp(ss) * scale;
        if (h == 0) att += xi;
        const int i_orig = g_perm[b][rank];
        atomicAdd(&out[b * DD + i_orig], att);
    }
}

extern "C" void kernel_launch(void* const* d_in, const int* in_sizes, int n_in,
                              void* d_out, int out_size, void* d_ws, size_t ws_size,
                              hipStream_t stream) {
    const float* x      = (const float*)d_in[0];
    const float* alphas = (const float*)d_in[1];
    const float* betas  = (const float*)d_in[2];
    float* out = (float*)d_out;

    hipMemsetAsync(out, 0, (size_t)out_size * sizeof(float), stream);

    sort_kernel<<<dim3(BB), dim3(DD), 0, stream>>>(x);

    dim3 grid(BB, 2, HH);
    dim3 block(512);
    flattn_kernel<<<grid, block, 0, stream>>>(x, alphas, betas, out);
}